// Round 6
// baseline (2649.935 us; speedup 1.0000x reference)
//
#include <hip/hip_runtime.h>
#include <hip/hip_fp16.h>

#define N_NODES 100000
#define N_EDGES 3200000
#define N_GRAPHS 64
#define IN_DIM 128
#define HIDDEN 64
#define LATENT 16

#define NBS 1024      // src buckets (128 nodes each), src>>7
#define NBD 1563      // dst buckets (64 nodes each), dst>>6
#define NBLK_PART 256
#define AGG_CAP 4096  // max edges per dst bucket (mean 2048, 45-sigma headroom)

// ---------------- tiny zero kernel ----------------
__global__ __launch_bounds__(256) void zero_k(int4* __restrict__ p, int n4) {
  int i = blockIdx.x * 256 + threadIdx.x;
  if (i < n4) p[i] = make_int4(0, 0, 0, 0);
}

// ---------------- pass A: bucket histograms (src: 1024x128, dst: 1563x64) ----
__global__ __launch_bounds__(256) void hist_k(const int4* __restrict__ src4,
                                              const int4* __restrict__ dst4,
                                              int* __restrict__ bc_src,
                                              int* __restrict__ bc_dst) {
  __shared__ int hs[NBS], hd[NBD];
  int t = threadIdx.x;
  for (int i = t; i < NBS; i += 256) hs[i] = 0;
  for (int i = t; i < NBD; i += 256) hd[i] = 0;
  __syncthreads();
  const int Q = N_EDGES / 4;          // 800000
  const int QPB = Q / NBLK_PART;      // 3125
  int q0 = blockIdx.x * QPB, q1 = q0 + QPB;
  for (int i = q0 + t; i < q1; i += 256) {
    int4 s = src4[i], d = dst4[i];
    atomicAdd(&hs[s.x >> 7], 1); atomicAdd(&hs[s.y >> 7], 1);
    atomicAdd(&hs[s.z >> 7], 1); atomicAdd(&hs[s.w >> 7], 1);
    atomicAdd(&hd[d.x >> 6], 1); atomicAdd(&hd[d.y >> 6], 1);
    atomicAdd(&hd[d.z >> 6], 1); atomicAdd(&hd[d.w >> 6], 1);
  }
  __syncthreads();
  for (int i = t; i < NBS; i += 256) if (hs[i]) atomicAdd(&bc_src[i], hs[i]);
  for (int i = t; i < NBD; i += 256) if (hd[i]) atomicAdd(&bc_dst[i], hd[i]);
}

// ---------------- pass B: exclusive scans -> bucket bases ----------------
__global__ __launch_bounds__(1024) void scan_k(const int* __restrict__ bc_src,
                                               const int* __restrict__ bc_dst,
                                               int* __restrict__ bbase_src,
                                               int* __restrict__ bbase_dst) {
  __shared__ int ts[1024];
  int t = threadIdx.x;
  // src side: 1024 entries, 1/thread
  int v = bc_src[t];
  ts[t] = v;
  __syncthreads();
  for (int off = 1; off < 1024; off <<= 1) {
    int x = 0;
    if (t >= off) x = ts[t - off];
    __syncthreads();
    if (t >= off) ts[t] += x;
    __syncthreads();
  }
  bbase_src[t] = ts[t] - v;
  if (t == 1023) bbase_src[1024] = ts[1023];
  __syncthreads();
  // dst side: 1563 entries, 2/thread
  int c0 = 2 * t;
  int v0 = (c0 < NBD) ? bc_dst[c0] : 0;
  int v1 = (c0 + 1 < NBD) ? bc_dst[c0 + 1] : 0;
  int s = v0 + v1;
  ts[t] = s;
  __syncthreads();
  for (int off = 1; off < 1024; off <<= 1) {
    int x = 0;
    if (t >= off) x = ts[t - off];
    __syncthreads();
    if (t >= off) ts[t] += x;
    __syncthreads();
  }
  int base = ts[t] - s;
  if (c0 < NBD) bbase_dst[c0] = base;
  if (c0 + 1 < NBD) bbase_dst[c0 + 1] = base + v0;
  if (t == 1023) bbase_dst[NBD] = ts[1023];
}

// ---------------- pass C: scatter src stream and packed (ldst6,src17) stream ----
__global__ __launch_bounds__(256) void scatter_k(const int4* __restrict__ src4,
                                                 const int4* __restrict__ dst4,
                                                 const int* __restrict__ bbase_src,
                                                 const int* __restrict__ bbase_dst,
                                                 int* __restrict__ cur_src,
                                                 int* __restrict__ cur_dst,
                                                 int* __restrict__ sortedS,
                                                 int* __restrict__ sortedE) {
  __shared__ int hs[NBS], hd[NBD];
  int t = threadIdx.x;
  for (int i = t; i < NBS; i += 256) hs[i] = 0;
  for (int i = t; i < NBD; i += 256) hd[i] = 0;
  __syncthreads();
  const int Q = N_EDGES / 4;
  const int QPB = Q / NBLK_PART;
  int q0 = blockIdx.x * QPB, q1 = q0 + QPB;
  for (int i = q0 + t; i < q1; i += 256) {
    int4 s = src4[i], d = dst4[i];
    atomicAdd(&hs[s.x >> 7], 1); atomicAdd(&hs[s.y >> 7], 1);
    atomicAdd(&hs[s.z >> 7], 1); atomicAdd(&hs[s.w >> 7], 1);
    atomicAdd(&hd[d.x >> 6], 1); atomicAdd(&hd[d.y >> 6], 1);
    atomicAdd(&hd[d.z >> 6], 1); atomicAdd(&hd[d.w >> 6], 1);
  }
  __syncthreads();
  // convert counts -> this block's running cursors (in place)
  for (int i = t; i < NBS; i += 256) {
    int a = hs[i];
    hs[i] = a ? (atomicAdd(&cur_src[i], a) + bbase_src[i]) : 0;
  }
  for (int i = t; i < NBD; i += 256) {
    int b = hd[i];
    hd[i] = b ? (atomicAdd(&cur_dst[i], b) + bbase_dst[i]) : 0;
  }
  __syncthreads();
  for (int i = q0 + t; i < q1; i += 256) {
    int4 s = src4[i], d = dst4[i];
    int sv[4] = {s.x, s.y, s.z, s.w};
    int dv[4] = {d.x, d.y, d.z, d.w};
#pragma unroll
    for (int k = 0; k < 4; k++) {
      int ps = atomicAdd(&hs[sv[k] >> 7], 1);
      sortedS[ps] = sv[k];
      int pd = atomicAdd(&hd[dv[k] >> 6], 1);
      sortedE[pd] = ((dv[k] & 63) << 17) | sv[k];
    }
  }
}

// ---------------- deg_out: per-src-bucket LDS hist over sortedS ----------------
__global__ __launch_bounds__(256) void degout_k(const int* __restrict__ sortedS,
                                                const int* __restrict__ bbase_src,
                                                int* __restrict__ deg_out) {
  __shared__ int h[128];
  int bk = blockIdx.x, t = threadIdx.x;
  if (t < 128) h[t] = 0;
  __syncthreads();
  int s0 = bbase_src[bk], s1 = bbase_src[bk + 1];
  for (int j = s0 + t; j < s1; j += 256) atomicAdd(&h[sortedS[j] & 127], 1);
  __syncthreads();
  if (t < 128) {
    int n = (bk << 7) | t;
    if (n < N_NODES) deg_out[n] = h[t];
  }
}

// ---------------- register-tiled GEMM: out[n][c] = (X@W)[n][c] * rsqrt(max(deg,1)) ----
// 64x64 block tile, 4x4 per-thread tile. IT selects f32/f16 input staging.
template <int IN, typename IT, typename OT>
__global__ __launch_bounds__(256) void gemm_tile_k(const IT* __restrict__ X,
                                                   const float* __restrict__ W,
                                                   const int* __restrict__ deg,
                                                   OT* __restrict__ out) {
  __shared__ float xs[64][IN + 4];
  __shared__ float ws[IN][HIDDEN];
  int t = threadIdx.x;
  int row0_blk = blockIdx.x * 64;

  for (int i = t; i < IN * HIDDEN / 4; i += 256)
    ((float4*)ws)[i] = ((const float4*)W)[i];
  for (int i = t; i < 64 * (IN / 4); i += 256) {
    int r = i / (IN / 4), c4 = i % (IN / 4);
    int row = row0_blk + r;
    float4 v = make_float4(0.f, 0.f, 0.f, 0.f);
    if (row < N_NODES) {
      if constexpr (sizeof(IT) == 4) {
        v = *(const float4*)&X[(size_t)row * IN + c4 * 4];
      } else {
        union { short4 s; __half2 h2[2]; } u;
        u.s = *(const short4*)&X[(size_t)row * IN + c4 * 4];
        float2 f0 = __half22float2(u.h2[0]);
        float2 f1 = __half22float2(u.h2[1]);
        v = make_float4(f0.x, f0.y, f1.x, f1.y);
      }
    }
    *(float4*)&xs[r][c4 * 4] = v;
  }
  __syncthreads();

  int w = t >> 6, lane = t & 63;
  int rg = lane >> 4, cg = lane & 15;
  int r0 = w * 16 + rg * 4;
  int c0 = cg * 4;

  float acc[4][4];
#pragma unroll
  for (int i = 0; i < 4; i++)
#pragma unroll
    for (int j = 0; j < 4; j++) acc[i][j] = 0.f;

#pragma unroll 4
  for (int d4 = 0; d4 < IN / 4; d4++) {
    float4 a0 = *(const float4*)&xs[r0 + 0][d4 * 4];
    float4 a1 = *(const float4*)&xs[r0 + 1][d4 * 4];
    float4 a2 = *(const float4*)&xs[r0 + 2][d4 * 4];
    float4 a3 = *(const float4*)&xs[r0 + 3][d4 * 4];
#pragma unroll
    for (int dd = 0; dd < 4; dd++) {
      float4 b = *(const float4*)&ws[d4 * 4 + dd][c0];
      float av0 = (&a0.x)[dd], av1 = (&a1.x)[dd], av2 = (&a2.x)[dd], av3 = (&a3.x)[dd];
      acc[0][0] += av0 * b.x; acc[0][1] += av0 * b.y; acc[0][2] += av0 * b.z; acc[0][3] += av0 * b.w;
      acc[1][0] += av1 * b.x; acc[1][1] += av1 * b.y; acc[1][2] += av1 * b.z; acc[1][3] += av1 * b.w;
      acc[2][0] += av2 * b.x; acc[2][1] += av2 * b.y; acc[2][2] += av2 * b.z; acc[2][3] += av2 * b.w;
      acc[3][0] += av3 * b.x; acc[3][1] += av3 * b.y; acc[3][2] += av3 * b.z; acc[3][3] += av3 * b.w;
    }
  }

#pragma unroll
  for (int i = 0; i < 4; i++) {
    int row = row0_blk + r0 + i;
    if (row >= N_NODES) continue;
    float dg = (float)deg[row];
    if (dg < 1.f) dg = 1.f;
    float sc = rsqrtf(dg);
    if constexpr (sizeof(OT) == 2) {
      __half2 p0 = __floats2half2_rn(acc[i][0] * sc, acc[i][1] * sc);
      __half2 p1 = __floats2half2_rn(acc[i][2] * sc, acc[i][3] * sc);
      union { __half2 h2[2]; float2 f2; } u;
      u.h2[0] = p0; u.h2[1] = p1;
      *(float2*)&out[(size_t)row * HIDDEN + c0] = u.f2;
    } else {
      float4 o = make_float4(acc[i][0] * sc, acc[i][1] * sc, acc[i][2] * sc, acc[i][3] * sc);
      *(float4*)&out[(size_t)row * HIDDEN + c0] = o;
    }
  }
}

// ---------------- aggregate: block = 64 dst nodes; LDS f32 accum; edges chunk-sorted ----
// out[n][c] = relu(rsqrt(max(deg_in,1)) * sum_{e->n} A[src_e][c] + b[c]), fp16 out.
__global__ __launch_bounds__(256) void agg_lds_k(const __half* __restrict__ A,
                                                 const int* __restrict__ sortedE,
                                                 const int* __restrict__ bbase_dst,
                                                 const float* __restrict__ bias,
                                                 __half* __restrict__ out) {
  __shared__ float acc[64][64];    // 16 KB
  __shared__ int edges[AGG_CAP];   // 16 KB
  __shared__ int cnt[64];
  __shared__ int cnt8[8];
  int bk = blockIdx.x, t = threadIdx.x;
  int e0 = bbase_dst[bk], e1 = bbase_dst[bk + 1];
  int m = e1 - e0;

  for (int i = t; i < 64 * 64 / 4; i += 256) ((float4*)acc)[i] = make_float4(0, 0, 0, 0);
  if (t < 64) cnt[t] = 0;
  if (t < 8) cnt8[t] = 0;
  __syncthreads();

  // pass 1: chunk histogram (src>>14, 7 used of 8) + per-node in-degree
  for (int j = e0 + t; j < e1; j += 256) {
    int v = sortedE[j];
    atomicAdd(&cnt8[(v & 0x1FFFF) >> 14], 1);
    atomicAdd(&cnt[v >> 17], 1);
  }
  __syncthreads();
  if (t == 0) {
    int run = 0;
#pragma unroll
    for (int c = 0; c < 8; c++) { int x = cnt8[c]; cnt8[c] = run; run += x; }
  }
  __syncthreads();
  // pass 2: count-sort edges by chunk into LDS (phase-aligns A reads across blocks)
  bool sorted = (m <= AGG_CAP);
  if (sorted) {
    for (int j = e0 + t; j < e1; j += 256) {
      int v = sortedE[j];
      int p = atomicAdd(&cnt8[(v & 0x1FFFF) >> 14], 1);
      edges[p] = v;
    }
  }
  __syncthreads();

  // main: half-wave (32 lanes) per edge; lane covers 2 channels via half2
  int hw = t >> 5, l = t & 31;
  int idx = hw;
  for (; idx + 24 < m; idx += 32) {
    int v0 = sorted ? edges[idx]      : sortedE[e0 + idx];
    int v1 = sorted ? edges[idx + 8]  : sortedE[e0 + idx + 8];
    int v2 = sorted ? edges[idx + 16] : sortedE[e0 + idx + 16];
    int v3 = sorted ? edges[idx + 24] : sortedE[e0 + idx + 24];
    float2 f0 = __half22float2(*(const __half2*)&A[(size_t)(v0 & 0x1FFFF) * HIDDEN + 2 * l]);
    float2 f1 = __half22float2(*(const __half2*)&A[(size_t)(v1 & 0x1FFFF) * HIDDEN + 2 * l]);
    float2 f2 = __half22float2(*(const __half2*)&A[(size_t)(v2 & 0x1FFFF) * HIDDEN + 2 * l]);
    float2 f3 = __half22float2(*(const __half2*)&A[(size_t)(v3 & 0x1FFFF) * HIDDEN + 2 * l]);
    atomicAdd(&acc[v0 >> 17][2 * l], f0.x); atomicAdd(&acc[v0 >> 17][2 * l + 1], f0.y);
    atomicAdd(&acc[v1 >> 17][2 * l], f1.x); atomicAdd(&acc[v1 >> 17][2 * l + 1], f1.y);
    atomicAdd(&acc[v2 >> 17][2 * l], f2.x); atomicAdd(&acc[v2 >> 17][2 * l + 1], f2.y);
    atomicAdd(&acc[v3 >> 17][2 * l], f3.x); atomicAdd(&acc[v3 >> 17][2 * l + 1], f3.y);
  }
  for (; idx < m; idx += 8) {
    int v = sorted ? edges[idx] : sortedE[e0 + idx];
    float2 f = __half22float2(*(const __half2*)&A[(size_t)(v & 0x1FFFF) * HIDDEN + 2 * l]);
    atomicAdd(&acc[v >> 17][2 * l], f.x);
    atomicAdd(&acc[v >> 17][2 * l + 1], f.y);
  }
  __syncthreads();

  // writeout: scale + bias + relu -> fp16
  for (int i = t; i < 64 * 64; i += 256) {
    int r = i >> 6, ch = i & 63;
    int node = (bk << 6) + r;
    if (node >= N_NODES) continue;
    float dg = (float)cnt[r];
    if (dg < 1.f) dg = 1.f;
    float v = acc[r][ch] * rsqrtf(dg) + bias[ch];
    out[(size_t)node * HIDDEN + ch] = __float2half(v > 0.f ? v : 0.f);
  }
}

// ---------------- per-graph mean pool (sorted node_graph, run-accumulate) ----------------
__global__ __launch_bounds__(256) void pool_k(const __half* __restrict__ h,
                                              const int* __restrict__ node_graph,
                                              float* __restrict__ sums,
                                              float* __restrict__ counts) {
  const int NPW = 256;  // nodes per wave
  int wave = (int)((blockIdx.x * blockDim.x + threadIdx.x) >> 6);
  int lane = threadIdx.x & 63;
  int start = wave * NPW;
  if (start >= N_NODES) return;
  int end = start + NPW; if (end > N_NODES) end = N_NODES;
  int cur = node_graph[start];
  float acc = 0.f, cnt = 0.f;
  for (int n = start; n < end; n++) {
    int g = node_graph[n];
    if (g != cur) {
      atomicAdd(&sums[cur * HIDDEN + lane], acc);
      if (lane == 0) atomicAdd(&counts[cur], cnt);
      cur = g; acc = 0.f; cnt = 0.f;
    }
    acc += __half2float(h[(size_t)n * HIDDEN + lane]);
    cnt += 1.f;
  }
  atomicAdd(&sums[cur * HIDDEN + lane], acc);
  if (lane == 0) atomicAdd(&counts[cur], cnt);
}

// ---------------- final: h_graph = sums/counts; mu/logvar = h_graph @ Wmu/Wlv + b ----------------
__global__ __launch_bounds__(256) void final_k(const float* __restrict__ sums,
                                               const float* __restrict__ counts,
                                               const float* __restrict__ Wmu,
                                               const float* __restrict__ bmu,
                                               const float* __restrict__ Wlv,
                                               const float* __restrict__ blv,
                                               float* __restrict__ out) {
  __shared__ float hg[N_GRAPHS][HIDDEN];
  __shared__ float wmu[HIDDEN][LATENT];
  __shared__ float wlv[HIDDEN][LATENT];
  int t = threadIdx.x;
  for (int i = t; i < N_GRAPHS * HIDDEN; i += 256) {
    int g = i / HIDDEN;
    float c = counts[g];
    if (c < 1.f) c = 1.f;
    hg[g][i % HIDDEN] = sums[i] / c;
  }
  for (int i = t; i < HIDDEN * LATENT; i += 256) {
    wmu[i / LATENT][i % LATENT] = Wmu[i];
    wlv[i / LATENT][i % LATENT] = Wlv[i];
  }
  __syncthreads();
  for (int i = t; i < N_GRAPHS * LATENT; i += 256) {
    int g = i / LATENT, j = i % LATENT;
    float mu = bmu[j], lv = blv[j];
#pragma unroll
    for (int k = 0; k < HIDDEN; k++) {
      float v = hg[g][k];
      mu += v * wmu[k][j];
      lv += v * wlv[k][j];
    }
    out[i] = mu;
    out[N_GRAPHS * LATENT + i] = lv;
  }
}

extern "C" void kernel_launch(void* const* d_in, const int* in_sizes, int n_in,
                              void* d_out, int out_size, void* d_ws, size_t ws_size,
                              hipStream_t stream) {
  const float* x = (const float*)d_in[0];
  // d_in[1] = edge_feat: provably unused for (mu, logvar)
  const int* src = (const int*)d_in[2];
  const int* dst = (const int*)d_in[3];
  const int* node_graph = (const int*)d_in[4];
  const float* W1 = (const float*)d_in[5];
  const float* b1 = (const float*)d_in[6];
  const float* W2 = (const float*)d_in[7];
  const float* b2 = (const float*)d_in[8];
  // d_in[9] = We, d_in[10] = be: unused
  const float* Wmu = (const float*)d_in[11];
  const float* bmu = (const float*)d_in[12];
  const float* Wlv = (const float*)d_in[13];
  const float* blv = (const float*)d_in[14];
  float* out = (float*)d_out;

  char* ws = (char*)d_ws;
  // zeroed control block [0, 37888)
  int* bc_src   = (int*)(ws + 0);        // 4096
  int* bc_dst   = (int*)(ws + 4096);     // 6400 (1563 used)
  int* cur_src  = (int*)(ws + 10496);    // 4096
  int* cur_dst  = (int*)(ws + 14592);    // 6400
  float* cnts   = (float*)(ws + 20992);  // 512
  float* sums   = (float*)(ws + 21504);  // 16384 -> 37888
  // non-zeroed control
  int* bbase_src = (int*)(ws + 37888);   // 4100 (pad 4352)
  int* bbase_dst = (int*)(ws + 42240);   // 6256 (pad 6400)
  // big arrays
  int* deg_out = (int*)(ws + 48640);     // 400128 -> 448768
  int* sortedS = (int*)(ws + 448768);    // 12800000 -> 13248768 (dead after degout_k)
  __half* B    = (__half*)(ws + 448768); // 12800000 alias of sortedS
  int* sortedE = (int*)(ws + 13248768);  // 12800000 -> 26048768 (live all layers)
  __half* A    = (__half*)(ws + 26048768);// 12800000 -> 38848768

  zero_k<<<(37888 / 16 + 255) / 256, 256, 0, stream>>>((int4*)ws, 37888 / 16);

  hist_k<<<NBLK_PART, 256, 0, stream>>>((const int4*)src, (const int4*)dst, bc_src, bc_dst);
  scan_k<<<1, 1024, 0, stream>>>(bc_src, bc_dst, bbase_src, bbase_dst);
  scatter_k<<<NBLK_PART, 256, 0, stream>>>((const int4*)src, (const int4*)dst,
                                           bbase_src, bbase_dst, cur_src, cur_dst,
                                           sortedS, sortedE);
  degout_k<<<782, 256, 0, stream>>>(sortedS, bbase_src, deg_out);

  const int GEMM_BLKS = (N_NODES + 63) / 64;  // 1563

  // layer 1: A = fp16((x @ W1) * deg_out^-1/2) ; B = fp16(relu(agg(A)*deg_in^-1/2 + b1))
  gemm_tile_k<IN_DIM, float, __half><<<GEMM_BLKS, 256, 0, stream>>>(x, W1, deg_out, A);
  agg_lds_k<<<NBD, 256, 0, stream>>>(A, sortedE, bbase_dst, b1, B);

  // layer 2: A = fp16((B @ W2) * deg_out^-1/2) ; B = fp16(relu(agg(A)*deg_in^-1/2 + b2))
  gemm_tile_k<HIDDEN, __half, __half><<<GEMM_BLKS, 256, 0, stream>>>(B, W2, deg_out, A);
  agg_lds_k<<<NBD, 256, 0, stream>>>(A, sortedE, bbase_dst, b2, B);

  // pool + heads
  pool_k<<<((N_NODES + 255) / 256 + 3) / 4, 256, 0, stream>>>(B, node_graph, sums, cnts);
  final_k<<<1, 256, 0, stream>>>(sums, cnts, Wmu, bmu, Wlv, blv, out);
}

// Round 7
// 439.404 us; speedup vs baseline: 6.0308x; 6.0308x over previous
//
#include <hip/hip_runtime.h>
#include <hip/hip_fp16.h>

#define N_NODES 100000
#define N_EDGES 3200000
#define N_GRAPHS 64
#define IN_DIM 128
#define HIDDEN 64
#define LATENT 16

#define NBUCK 1024
#define BSHIFT 7
#define NODES_PER_BUCK 128
#define NBLK_PART 256
#define NB_USED ((N_NODES + NODES_PER_BUCK - 1) / NODES_PER_BUCK)  // 782

// ---------------- tiny zero kernel ----------------
__global__ __launch_bounds__(256) void zero_k(int4* __restrict__ p, int n4) {
  int i = blockIdx.x * 256 + threadIdx.x;
  if (i < n4) p[i] = make_int4(0, 0, 0, 0);
}

// ---------------- pass A: 1024-bucket histograms; also dump per-block counts ----
__global__ __launch_bounds__(256) void bucket_hist_k(const int4* __restrict__ src4,
                                                     const int4* __restrict__ dst4,
                                                     int* __restrict__ bc_src,
                                                     int* __restrict__ bc_dst,
                                                     int* __restrict__ tbl_src,
                                                     int* __restrict__ tbl_dst) {
  __shared__ int hs[NBUCK], hd[NBUCK];
  int t = threadIdx.x;
  for (int i = t; i < NBUCK; i += 256) { hs[i] = 0; hd[i] = 0; }
  __syncthreads();
  const int Q = N_EDGES / 4;          // 800000
  const int QPB = Q / NBLK_PART;      // 3125
  int q0 = blockIdx.x * QPB, q1 = q0 + QPB;
  for (int i = q0 + t; i < q1; i += 256) {
    int4 s = src4[i], d = dst4[i];
    atomicAdd(&hs[s.x >> BSHIFT], 1); atomicAdd(&hs[s.y >> BSHIFT], 1);
    atomicAdd(&hs[s.z >> BSHIFT], 1); atomicAdd(&hs[s.w >> BSHIFT], 1);
    atomicAdd(&hd[d.x >> BSHIFT], 1); atomicAdd(&hd[d.y >> BSHIFT], 1);
    atomicAdd(&hd[d.z >> BSHIFT], 1); atomicAdd(&hd[d.w >> BSHIFT], 1);
  }
  __syncthreads();
  for (int i = t; i < NBUCK; i += 256) {
    int a = hs[i], b = hd[i];
    tbl_src[blockIdx.x * NBUCK + i] = a;
    tbl_dst[blockIdx.x * NBUCK + i] = b;
    if (a) atomicAdd(&bc_src[i], a);
    if (b) atomicAdd(&bc_dst[i], b);
  }
}

// ---------------- pass B: exclusive scan of both bucket-count arrays ----------------
__global__ __launch_bounds__(1024) void bucket_scan_k(const int* __restrict__ bc_src,
                                                      const int* __restrict__ bc_dst,
                                                      int* __restrict__ bbase_src,
                                                      int* __restrict__ bbase_dst,
                                                      int* __restrict__ row_ptr) {
  __shared__ int a[NBUCK], b[NBUCK];
  int t = threadIdx.x;
  int va = bc_src[t], vb = bc_dst[t];
  a[t] = va; b[t] = vb;
  __syncthreads();
  for (int off = 1; off < NBUCK; off <<= 1) {
    int xa = 0, xb = 0;
    if (t >= off) { xa = a[t - off]; xb = b[t - off]; }
    __syncthreads();
    if (t >= off) { a[t] += xa; b[t] += xb; }
    __syncthreads();
  }
  bbase_src[t] = a[t] - va;
  bbase_dst[t] = b[t] - vb;
  if (t == NBUCK - 1) {
    bbase_src[NBUCK] = a[t];
    bbase_dst[NBUCK] = b[t];
    row_ptr[N_NODES] = N_EDGES;
  }
}

// ---------------- pass C: scatter using precomputed per-block counts ----------------
__global__ __launch_bounds__(256) void scatter_k(const int4* __restrict__ src4,
                                                 const int4* __restrict__ dst4,
                                                 const int* __restrict__ bbase_src,
                                                 const int* __restrict__ bbase_dst,
                                                 const int* __restrict__ tbl_src,
                                                 const int* __restrict__ tbl_dst,
                                                 int* __restrict__ cur_src,
                                                 int* __restrict__ cur_dst,
                                                 int* __restrict__ sortedS,
                                                 int* __restrict__ sortedE) {
  __shared__ int rs[NBUCK], rd[NBUCK];
  int t = threadIdx.x;
  for (int i = t; i < NBUCK; i += 256) {
    int a = tbl_src[blockIdx.x * NBUCK + i];
    int b = tbl_dst[blockIdx.x * NBUCK + i];
    rs[i] = a ? (atomicAdd(&cur_src[i], a) + bbase_src[i]) : 0;
    rd[i] = b ? (atomicAdd(&cur_dst[i], b) + bbase_dst[i]) : 0;
  }
  __syncthreads();
  const int Q = N_EDGES / 4;
  const int QPB = Q / NBLK_PART;
  int q0 = blockIdx.x * QPB, q1 = q0 + QPB;
  for (int i = q0 + t; i < q1; i += 256) {
    int4 s = src4[i], d = dst4[i];
    int sv[4] = {s.x, s.y, s.z, s.w};
    int dv[4] = {d.x, d.y, d.z, d.w};
#pragma unroll
    for (int k = 0; k < 4; k++) {
      int ps = atomicAdd(&rs[sv[k] >> BSHIFT], 1);
      sortedS[ps] = sv[k];
      int pd = atomicAdd(&rd[dv[k] >> BSHIFT], 1);
      sortedE[pd] = ((dv[k] & (NODES_PER_BUCK - 1)) << 17) | sv[k];
    }
  }
}

// ---------------- pass D: per-bucket CSR with (node, src-chunk) key ordering ----------
// key = (local_dst << 3) | (src >> 14): each node's csr list comes out chunk-ordered
// (7 chunks of 2 MB of A), phase-aligning gathers across the whole GPU.
__global__ __launch_bounds__(256) void bucket_csr_k(const int* __restrict__ sortedS,
                                                    const int* __restrict__ sortedE,
                                                    const int* __restrict__ bbase_src,
                                                    const int* __restrict__ bbase_dst,
                                                    int* __restrict__ deg_out,
                                                    int* __restrict__ deg_in,
                                                    int* __restrict__ row_ptr,
                                                    int* __restrict__ csr_src) {
  __shared__ int hout[NODES_PER_BUCK];
  __shared__ int hkey[1024];
  __shared__ int skey[1024];
  __shared__ int ts[256];
  int bk = blockIdx.x, t = threadIdx.x;
  int node0 = bk << BSHIFT;
  if (t < NODES_PER_BUCK) hout[t] = 0;
  for (int i = t; i < 1024; i += 256) hkey[i] = 0;
  __syncthreads();
  int s0 = bbase_src[bk], s1 = bbase_src[bk + 1];
  for (int j = s0 + t; j < s1; j += 256)
    atomicAdd(&hout[sortedS[j] & (NODES_PER_BUCK - 1)], 1);
  int e0 = bbase_dst[bk], e1 = bbase_dst[bk + 1];
  for (int j = e0 + t; j < e1; j += 256) {
    int v = sortedE[j];
    atomicAdd(&hkey[((v >> 17) << 3) | ((v & 0x1FFFF) >> 14)], 1);
  }
  __syncthreads();
  // exclusive scan over 1024 keys (4 per thread + block scan of 256)
  int b4 = 4 * t;
  int a0 = hkey[b4], a1 = hkey[b4 + 1], a2 = hkey[b4 + 2], a3 = hkey[b4 + 3];
  int tot = a0 + a1 + a2 + a3;
  ts[t] = tot;
  __syncthreads();
  for (int off = 1; off < 256; off <<= 1) {
    int x = 0;
    if (t >= off) x = ts[t - off];
    __syncthreads();
    if (t >= off) ts[t] += x;
    __syncthreads();
  }
  int run = ts[t] - tot;
  skey[b4] = run;
  skey[b4 + 1] = run + a0;
  skey[b4 + 2] = run + a0 + a1;
  skey[b4 + 3] = run + a0 + a1 + a2;
  __syncthreads();
  // degrees + row_ptr (uses skey and hkey)
  if (t < NODES_PER_BUCK) {
    int n = node0 + t;
    if (n < N_NODES) {
      deg_out[n] = hout[t];
      int k0 = t << 3;
      deg_in[n] = skey[k0 + 7] + hkey[k0 + 7] - skey[k0];
      row_ptr[n] = e0 + skey[k0];
    }
  }
  __syncthreads();
  // reuse hkey as cursors, scatter csr in (node, chunk) order
  for (int i = t; i < 1024; i += 256) hkey[i] = 0;
  __syncthreads();
  for (int j = e0 + t; j < e1; j += 256) {
    int v = sortedE[j];
    int key = ((v >> 17) << 3) | ((v & 0x1FFFF) >> 14);
    int pos = e0 + skey[key] + atomicAdd(&hkey[key], 1);
    csr_src[pos] = v & 0x1FFFF;
  }
}

// ---------------- register-tiled GEMM: out[n][c] = (X@W)[n][c] * rsqrt(max(deg,1)) ----
template <int IN, typename IT, typename OT>
__global__ __launch_bounds__(256) void gemm_tile_k(const IT* __restrict__ X,
                                                   const float* __restrict__ W,
                                                   const int* __restrict__ deg,
                                                   OT* __restrict__ out) {
  __shared__ float xs[64][IN + 4];
  __shared__ float ws[IN][HIDDEN];
  int t = threadIdx.x;
  int row0_blk = blockIdx.x * 64;

  for (int i = t; i < IN * HIDDEN / 4; i += 256)
    ((float4*)ws)[i] = ((const float4*)W)[i];
  for (int i = t; i < 64 * (IN / 4); i += 256) {
    int r = i / (IN / 4), c4 = i % (IN / 4);
    int row = row0_blk + r;
    float4 v = make_float4(0.f, 0.f, 0.f, 0.f);
    if (row < N_NODES) {
      if constexpr (sizeof(IT) == 4) {
        v = *(const float4*)&X[(size_t)row * IN + c4 * 4];
      } else {
        union { short4 s; __half2 h2[2]; } u;
        u.s = *(const short4*)&X[(size_t)row * IN + c4 * 4];
        float2 f0 = __half22float2(u.h2[0]);
        float2 f1 = __half22float2(u.h2[1]);
        v = make_float4(f0.x, f0.y, f1.x, f1.y);
      }
    }
    *(float4*)&xs[r][c4 * 4] = v;
  }
  __syncthreads();

  int w = t >> 6, lane = t & 63;
  int rg = lane >> 4, cg = lane & 15;
  int r0 = w * 16 + rg * 4;
  int c0 = cg * 4;

  float acc[4][4];
#pragma unroll
  for (int i = 0; i < 4; i++)
#pragma unroll
    for (int j = 0; j < 4; j++) acc[i][j] = 0.f;

#pragma unroll 4
  for (int d4 = 0; d4 < IN / 4; d4++) {
    float4 a0 = *(const float4*)&xs[r0 + 0][d4 * 4];
    float4 a1 = *(const float4*)&xs[r0 + 1][d4 * 4];
    float4 a2 = *(const float4*)&xs[r0 + 2][d4 * 4];
    float4 a3 = *(const float4*)&xs[r0 + 3][d4 * 4];
#pragma unroll
    for (int dd = 0; dd < 4; dd++) {
      float4 b = *(const float4*)&ws[d4 * 4 + dd][c0];
      float av0 = (&a0.x)[dd], av1 = (&a1.x)[dd], av2 = (&a2.x)[dd], av3 = (&a3.x)[dd];
      acc[0][0] += av0 * b.x; acc[0][1] += av0 * b.y; acc[0][2] += av0 * b.z; acc[0][3] += av0 * b.w;
      acc[1][0] += av1 * b.x; acc[1][1] += av1 * b.y; acc[1][2] += av1 * b.z; acc[1][3] += av1 * b.w;
      acc[2][0] += av2 * b.x; acc[2][1] += av2 * b.y; acc[2][2] += av2 * b.z; acc[2][3] += av2 * b.w;
      acc[3][0] += av3 * b.x; acc[3][1] += av3 * b.y; acc[3][2] += av3 * b.z; acc[3][3] += av3 * b.w;
    }
  }

#pragma unroll
  for (int i = 0; i < 4; i++) {
    int row = row0_blk + r0 + i;
    if (row >= N_NODES) continue;
    float dg = (float)deg[row];
    if (dg < 1.f) dg = 1.f;
    float sc = rsqrtf(dg);
    if constexpr (sizeof(OT) == 2) {
      __half2 p0 = __floats2half2_rn(acc[i][0] * sc, acc[i][1] * sc);
      __half2 p1 = __floats2half2_rn(acc[i][2] * sc, acc[i][3] * sc);
      union { __half2 h2[2]; float2 f2; } u;
      u.h2[0] = p0; u.h2[1] = p1;
      *(float2*)&out[(size_t)row * HIDDEN + c0] = u.f2;
    } else {
      float4 o = make_float4(acc[i][0] * sc, acc[i][1] * sc, acc[i][2] * sc, acc[i][3] * sc);
      *(float4*)&out[(size_t)row * HIDDEN + c0] = o;
    }
  }
}

// ---------------- aggregate (fp16 gather, fp32 regs, fp16 out) ----------------
__global__ __launch_bounds__(256) void aggregate_k(const __half* __restrict__ hw,
                                                   const int* __restrict__ row_ptr,
                                                   const int* __restrict__ csr_src,
                                                   const int* __restrict__ deg_in,
                                                   const float* __restrict__ bias,
                                                   __half* __restrict__ out) {
  int wave = (int)((blockIdx.x * blockDim.x + threadIdx.x) >> 6);
  int lane = threadIdx.x & 63;
  if (wave >= N_NODES) return;
  int start = row_ptr[wave], end = row_ptr[wave + 1];
  float acc = 0.f;
  int j = start;
  for (; j + 15 < end; j += 16) {
    int idx[16];
#pragma unroll
    for (int k = 0; k < 16; k++) idx[k] = csr_src[j + k];
    float a[16];
#pragma unroll
    for (int k = 0; k < 16; k++) a[k] = __half2float(hw[(size_t)idx[k] * HIDDEN + lane]);
    float s01 = (a[0] + a[1]) + (a[2] + a[3]);
    float s23 = (a[4] + a[5]) + (a[6] + a[7]);
    float s45 = (a[8] + a[9]) + (a[10] + a[11]);
    float s67 = (a[12] + a[13]) + (a[14] + a[15]);
    acc += (s01 + s23) + (s45 + s67);
  }
  for (; j + 7 < end; j += 8) {
    int idx[8];
#pragma unroll
    for (int k = 0; k < 8; k++) idx[k] = csr_src[j + k];
    float a[8];
#pragma unroll
    for (int k = 0; k < 8; k++) a[k] = __half2float(hw[(size_t)idx[k] * HIDDEN + lane]);
    acc += ((a[0] + a[1]) + (a[2] + a[3])) + ((a[4] + a[5]) + (a[6] + a[7]));
  }
  for (; j < end; j++) {
    int s = csr_src[j];
    acc += __half2float(hw[(size_t)s * HIDDEN + lane]);
  }
  float dg = (float)deg_in[wave];
  if (dg < 1.f) dg = 1.f;
  float v = acc * rsqrtf(dg) + bias[lane];
  out[(size_t)wave * HIDDEN + lane] = __float2half(v > 0.f ? v : 0.f);
}

// ---------------- per-graph mean pool (sorted node_graph, run-accumulate) ----------------
__global__ __launch_bounds__(256) void pool_k(const __half* __restrict__ h,
                                              const int* __restrict__ node_graph,
                                              float* __restrict__ sums,
                                              float* __restrict__ counts) {
  const int NPW = 256;  // nodes per wave
  int wave = (int)((blockIdx.x * blockDim.x + threadIdx.x) >> 6);
  int lane = threadIdx.x & 63;
  int start = wave * NPW;
  if (start >= N_NODES) return;
  int end = start + NPW; if (end > N_NODES) end = N_NODES;
  int cur = node_graph[start];
  float acc = 0.f, cnt = 0.f;
  for (int n = start; n < end; n++) {
    int g = node_graph[n];
    if (g != cur) {
      atomicAdd(&sums[cur * HIDDEN + lane], acc);
      if (lane == 0) atomicAdd(&counts[cur], cnt);
      cur = g; acc = 0.f; cnt = 0.f;
    }
    acc += __half2float(h[(size_t)n * HIDDEN + lane]);
    cnt += 1.f;
  }
  atomicAdd(&sums[cur * HIDDEN + lane], acc);
  if (lane == 0) atomicAdd(&counts[cur], cnt);
}

// ---------------- final: h_graph = sums/counts; mu/logvar = h_graph @ Wmu/Wlv + b ----------------
__global__ __launch_bounds__(256) void final_k(const float* __restrict__ sums,
                                               const float* __restrict__ counts,
                                               const float* __restrict__ Wmu,
                                               const float* __restrict__ bmu,
                                               const float* __restrict__ Wlv,
                                               const float* __restrict__ blv,
                                               float* __restrict__ out) {
  __shared__ float hg[N_GRAPHS][HIDDEN];
  __shared__ float wmu[HIDDEN][LATENT];
  __shared__ float wlv[HIDDEN][LATENT];
  int t = threadIdx.x;
  for (int i = t; i < N_GRAPHS * HIDDEN; i += 256) {
    int g = i / HIDDEN;
    float c = counts[g];
    if (c < 1.f) c = 1.f;
    hg[g][i % HIDDEN] = sums[i] / c;
  }
  for (int i = t; i < HIDDEN * LATENT; i += 256) {
    wmu[i / LATENT][i % LATENT] = Wmu[i];
    wlv[i / LATENT][i % LATENT] = Wlv[i];
  }
  __syncthreads();
  for (int i = t; i < N_GRAPHS * LATENT; i += 256) {
    int g = i / LATENT, j = i % LATENT;
    float mu = bmu[j], lv = blv[j];
#pragma unroll
    for (int k = 0; k < HIDDEN; k++) {
      float v = hg[g][k];
      mu += v * wmu[k][j];
      lv += v * wlv[k][j];
    }
    out[i] = mu;
    out[N_GRAPHS * LATENT + i] = lv;
  }
}

extern "C" void kernel_launch(void* const* d_in, const int* in_sizes, int n_in,
                              void* d_out, int out_size, void* d_ws, size_t ws_size,
                              hipStream_t stream) {
  const float* x = (const float*)d_in[0];
  // d_in[1] = edge_feat: provably unused for (mu, logvar)
  const int* src = (const int*)d_in[2];
  const int* dst = (const int*)d_in[3];
  const int* node_graph = (const int*)d_in[4];
  const float* W1 = (const float*)d_in[5];
  const float* b1 = (const float*)d_in[6];
  const float* W2 = (const float*)d_in[7];
  const float* b2 = (const float*)d_in[8];
  // d_in[9] = We, d_in[10] = be: unused
  const float* Wmu = (const float*)d_in[11];
  const float* bmu = (const float*)d_in[12];
  const float* Wlv = (const float*)d_in[13];
  const float* blv = (const float*)d_in[14];
  float* out = (float*)d_out;

  char* ws = (char*)d_ws;
  // zeroed control block [0, 33280)
  int* bc_src   = (int*)(ws + 0);        // 4096
  int* bc_dst   = (int*)(ws + 4096);     // 4096
  int* cur_src  = (int*)(ws + 8192);     // 4096
  int* cur_dst  = (int*)(ws + 12288);    // 4096
  float* cnts   = (float*)(ws + 16384);  // 512
  float* sums   = (float*)(ws + 16896);  // 16384 -> 33280
  // non-zeroed control
  int* bbase_src = (int*)(ws + 33280);   // 4100 (pad to 37632)
  int* bbase_dst = (int*)(ws + 37632);   // 4100 (pad to 41984)
  int* tbl_src   = (int*)(ws + 41984);   // 1048576
  int* tbl_dst   = (int*)(ws + 1090560); // 1048576 -> 2139136
  // big arrays
  int* deg_out = (int*)(ws + 2139136);   // 400128
  int* deg_in  = (int*)(ws + 2539264);   // 400128
  int* row_ptr = (int*)(ws + 2939392);   // 400128 -> 3339520
  int* csr_src = (int*)(ws + 3339520);   // 12800000 -> 16139520
  int* sortedS = (int*)(ws + 16139520);  // 12800000 -> 28939520 (dead after csr pass)
  int* sortedE = (int*)(ws + 28939520);  // 12800000 -> 41739520 (dead after csr pass)
  __half* A    = (__half*)(ws + 16139520); // 12800000, alias of sortedS
  __half* B    = (__half*)(ws + 28939520); // 12800000, alias of sortedE

  zero_k<<<(33280 / 16 + 255) / 256, 256, 0, stream>>>((int4*)ws, 33280 / 16);

  bucket_hist_k<<<NBLK_PART, 256, 0, stream>>>((const int4*)src, (const int4*)dst,
                                               bc_src, bc_dst, tbl_src, tbl_dst);
  bucket_scan_k<<<1, 1024, 0, stream>>>(bc_src, bc_dst, bbase_src, bbase_dst, row_ptr);
  scatter_k<<<NBLK_PART, 256, 0, stream>>>((const int4*)src, (const int4*)dst,
                                           bbase_src, bbase_dst, tbl_src, tbl_dst,
                                           cur_src, cur_dst, sortedS, sortedE);
  bucket_csr_k<<<NB_USED, 256, 0, stream>>>(sortedS, sortedE, bbase_src, bbase_dst,
                                            deg_out, deg_in, row_ptr, csr_src);

  const int GEMM_BLKS = (N_NODES + 63) / 64;  // 1563

  // layer 1: A = fp16((x @ W1) * deg_out^-1/2) ; B = fp16(relu(agg(A)*deg_in^-1/2 + b1))
  gemm_tile_k<IN_DIM, float, __half><<<GEMM_BLKS, 256, 0, stream>>>(x, W1, deg_out, A);
  aggregate_k<<<(N_NODES + 3) / 4, 256, 0, stream>>>(A, row_ptr, csr_src, deg_in, b1, B);

  // layer 2: A = fp16((B @ W2) * deg_out^-1/2) ; B = fp16(relu(agg(A)*deg_in^-1/2 + b2))
  gemm_tile_k<HIDDEN, __half, __half><<<GEMM_BLKS, 256, 0, stream>>>(B, W2, deg_out, A);
  aggregate_k<<<(N_NODES + 3) / 4, 256, 0, stream>>>(A, row_ptr, csr_src, deg_in, b2, B);

  // pool + heads
  pool_k<<<((N_NODES + 255) / 256 + 3) / 4, 256, 0, stream>>>(B, node_graph, sums, cnts);
  final_k<<<1, 256, 0, stream>>>(sums, cnts, Wmu, bmu, Wlv, blv, out);
}